// Round 9
// baseline (386.709 us; speedup 1.0000x reference)
//
#include <hip/hip_runtime.h>

// GCN 3-layer fused pipeline for MI355X.
// N=50000 nodes, E=800000 edges, F=128 features.
// edge_index staged as int32, layout [row[0..E), col[0..E)].
// Per layer: g = dinv * (X' @ W)  (X' = relu(dinv*agg_prev + b_prev) fused into load)
//            agg[v] = g[v] + sum_{in-edges} g[src]  (CSR gather, no atomics)
// R2:  wave-per-node float4 gathers: 85->58us (3.7 TB/s).
// R5:  deeper pipeline: 58->61us — occupancy fell 67->46% (VGPR 20->40); net zero.
//      FETCH 185MB = 8 XCDs x 23MB: every XCD L2 (4MB) refetches the whole 25.6MB
//      gather set. Capacity problem, not concurrency.
// R6:  feature-sliced gather: g stored slice-major [8][N][16 floats]; block->slice
//      by blockIdx%8 (XCD round-robin heuristic) => per-XCD random set 3.2MB fits L2.
//      csr/offs via nontemporal loads, agg via nontemporal stores (don't evict slice).
//      Lane-quad = one 64B slice line; 8 edges in flight/quad; no reduction shuffles.
//      GEMM: 64-row tiles, 8x4 acc, 48KB LDS (3 blocks/CU).
// R7:  fix compile: nontemporal_store via ext_vector_type(4) float.
// R8:  identical resubmit (R7 bench lost to GPU acquisition timeout).

#define SLICES 8

typedef float nfloat4 __attribute__((ext_vector_type(4)));

__global__ __launch_bounds__(256) void k_prep(const int* __restrict__ ei,
                                              int* __restrict__ cnt, int E, int N) {
  int e = blockIdx.x * 256 + threadIdx.x;
  if (e < E) {
    unsigned c = (unsigned)ei[E + e];
    if (c < (unsigned)N) atomicAdd(&cnt[c], 1);
  }
}

// block-local exclusive scan of cnt; also emits dinv (fused)
__global__ __launch_bounds__(256) void k_scan1(const int* __restrict__ cnt, int* __restrict__ offs,
                                               int* __restrict__ bsum, float* __restrict__ dinv, int N) {
  __shared__ int s[256];
  int tid = threadIdx.x;
  int i = blockIdx.x * 256 + tid;
  int v = (i < N) ? cnt[i] : 0;
  if (i < N) dinv[i] = rsqrtf((float)(v + 1));  // +1 self loop; always > 0
  s[tid] = v;
  __syncthreads();
  for (int d = 1; d < 256; d <<= 1) {
    int t = (tid >= d) ? s[tid - d] : 0;
    __syncthreads();
    s[tid] += t;
    __syncthreads();
  }
  if (i < N) offs[i] = s[tid] - v;
  if (tid == 255) bsum[blockIdx.x] = s[255];
}

__global__ __launch_bounds__(256) void k_scan2(int* __restrict__ bsum, int B) {
  __shared__ int s[256];
  int tid = threadIdx.x;
  int v = (tid < B) ? bsum[tid] : 0;
  s[tid] = v;
  __syncthreads();
  for (int d = 1; d < 256; d <<= 1) {
    int t = (tid >= d) ? s[tid - d] : 0;
    __syncthreads();
    s[tid] += t;
    __syncthreads();
  }
  if (tid < B) bsum[tid] = s[tid] - v;
}

__global__ __launch_bounds__(256) void k_scan3(int* __restrict__ offs, const int* __restrict__ bsum,
                                               int* __restrict__ cursor, int N, int E) {
  int i = blockIdx.x * 256 + threadIdx.x;
  if (i < N) {
    int o = offs[i] + bsum[blockIdx.x];
    offs[i] = o;
    cursor[i] = o;
  }
  if (i == 0) offs[N] = E;
}

__global__ __launch_bounds__(256) void k_fill(const int* __restrict__ ei,
                                              int* __restrict__ cursor, int* __restrict__ csr_src,
                                              int E, int N) {
  int e = blockIdx.x * 256 + threadIdx.x;
  if (e < E) {
    unsigned r = (unsigned)ei[e];
    unsigned c = (unsigned)ei[E + e];
    if (c < (unsigned)N && r < (unsigned)N) {
      int p = atomicAdd(&cursor[c], 1);
      csr_src[p] = (int)r;
    }
  }
}

// GEMM: G[s][row][16f] = dinv[row] * sum_k X'[row][k] * W[k][col], slice-major out.
// MODE 0: X' = X (row-major input).
// MODE 1: X'[r][k] = relu(dinv[r]*X[r][k] + bias[k]), X slice-major [8][N][16].
// 256 thr -> 64 rows x 128 cols; thread = 8 rows x 4 cols. LDS 48KB -> 3 blocks/CU.
template <int MODE>
__global__ __launch_bounds__(256) void k_gemm(const float* __restrict__ X, const float* __restrict__ W,
                                              const float* __restrict__ dinv, const float* __restrict__ bias,
                                              float* __restrict__ G, int N) {
  __shared__ float Wl[32 * 128];   // 16 KB (K-chunk of 32)
  __shared__ float Xl[64 * 128];   // 32 KB
  int tid = threadIdx.x;
  int row0 = blockIdx.x * 64;

  for (int i = tid; i < 2048; i += 256) {
    int r = i >> 5;
    int cc = i & 31;   // float4 column index; original col base = cc*4
    int grow = row0 + r;
    int gr = (grow < N) ? grow : (N - 1);
    float4 v;
    if (MODE == 0) {
      v = ((const float4*)X)[(size_t)gr * 32 + cc];
    } else {
      v = ((const float4*)X)[((size_t)(cc >> 2) * N + gr) * 4 + (cc & 3)];
      float di = dinv[gr];
      v.x = fmaxf(fmaf(di, v.x, bias[cc * 4 + 0]), 0.f);
      v.y = fmaxf(fmaf(di, v.y, bias[cc * 4 + 1]), 0.f);
      v.z = fmaxf(fmaf(di, v.z, bias[cc * 4 + 2]), 0.f);
      v.w = fmaxf(fmaf(di, v.w, bias[cc * 4 + 3]), 0.f);
    }
    ((float4*)Xl)[i] = v;
  }

  int cg = tid & 31;   // col group: cols cg*4..cg*4+3
  int rg = tid >> 5;   // row group: rows rg*8..rg*8+7
  float acc[8][4];
#pragma unroll
  for (int a = 0; a < 8; a++)
#pragma unroll
    for (int b = 0; b < 4; b++) acc[a][b] = 0.f;

  for (int kt = 0; kt < 4; kt++) {
    __syncthreads();  // Xl ready (kt=0) / previous Wl reads done
    for (int i = tid; i < 1024; i += 256)
      ((float4*)Wl)[i] = ((const float4*)W)[kt * 1024 + i];
    __syncthreads();
#pragma unroll
    for (int k4 = 0; k4 < 8; k4++) {
      float4 wv[4];
#pragma unroll
      for (int kk = 0; kk < 4; kk++)
        wv[kk] = ((const float4*)(Wl + (k4 * 4 + kk) * 128))[cg];
#pragma unroll
      for (int r = 0; r < 8; r++) {
        float4 xv = *(const float4*)(Xl + (rg * 8 + r) * 128 + kt * 32 + k4 * 4);
        acc[r][0] = fmaf(xv.x, wv[0].x, acc[r][0]);
        acc[r][1] = fmaf(xv.x, wv[0].y, acc[r][1]);
        acc[r][2] = fmaf(xv.x, wv[0].z, acc[r][2]);
        acc[r][3] = fmaf(xv.x, wv[0].w, acc[r][3]);
        acc[r][0] = fmaf(xv.y, wv[1].x, acc[r][0]);
        acc[r][1] = fmaf(xv.y, wv[1].y, acc[r][1]);
        acc[r][2] = fmaf(xv.y, wv[1].z, acc[r][2]);
        acc[r][3] = fmaf(xv.y, wv[1].w, acc[r][3]);
        acc[r][0] = fmaf(xv.z, wv[2].x, acc[r][0]);
        acc[r][1] = fmaf(xv.z, wv[2].y, acc[r][1]);
        acc[r][2] = fmaf(xv.z, wv[2].z, acc[r][2]);
        acc[r][3] = fmaf(xv.z, wv[2].w, acc[r][3]);
        acc[r][0] = fmaf(xv.w, wv[3].x, acc[r][0]);
        acc[r][1] = fmaf(xv.w, wv[3].y, acc[r][1]);
        acc[r][2] = fmaf(xv.w, wv[3].z, acc[r][2]);
        acc[r][3] = fmaf(xv.w, wv[3].w, acc[r][3]);
      }
    }
  }

  int s = cg >> 2, f4 = cg & 3;
#pragma unroll
  for (int ri = 0; ri < 8; ri++) {
    int grow = row0 + rg * 8 + ri;
    if (grow < N) {
      float di = dinv[grow];
      float4 o;
      o.x = di * acc[ri][0];
      o.y = di * acc[ri][1];
      o.z = di * acc[ri][2];
      o.w = di * acc[ri][3];
      ((float4*)G)[((size_t)s * N + grow) * 4 + f4] = o;
    }
  }
}

// Sliced aggregation: agg[s][v] = g[s][v] + sum_{in-edges} g[s][src].
// Block b: slice = b%8 (-> XCD b%8 by round-robin dispatch), 64 nodes per block,
// one node per lane-quad (4 lanes x float4 = the 64B slice line).
// 8 edges in flight per quad; masked tail; no reduction shuffles needed.
__global__ __launch_bounds__(256) void k_agg(const float* __restrict__ g, const int* __restrict__ offs,
                                             const int* __restrict__ csr, float* __restrict__ agg, int N) {
  int s = blockIdx.x & 7;
  int chunk = blockIdx.x >> 3;
  int tid = threadIdx.x;
  int v = chunk * 64 + (tid >> 2);
  if (v >= N) return;
  int ql = tid & 3;
  int q4 = (tid & 63) & ~3;   // quad base lane within wave
  const float4* __restrict__ G4 = (const float4*)g;
  size_t sb = (size_t)s * N;

  float4 a = G4[(sb + v) * 4 + ql];   // self row slice
  int s0 = offs[v], s1 = offs[v + 1];
  int last = s1 - 1;

  for (int i = s0; i < s1; i += 8) {
    int ja = i + ql;
    int jb = i + 4 + ql;
    int ia = __builtin_nontemporal_load(&csr[ja < last ? ja : last]);
    int ib = __builtin_nontemporal_load(&csr[jb < last ? jb : last]);
    int srcs[8];
#pragma unroll
    for (int k = 0; k < 4; k++) srcs[k] = __shfl(ia, q4 + k, 64);
#pragma unroll
    for (int k = 0; k < 4; k++) srcs[4 + k] = __shfl(ib, q4 + k, 64);
    float4 r[8];
#pragma unroll
    for (int k = 0; k < 8; k++) r[k] = G4[(sb + (size_t)srcs[k]) * 4 + ql];
#pragma unroll
    for (int k = 0; k < 8; k++) {
      float sc = (i + k < s1) ? 1.f : 0.f;
      a.x = fmaf(sc, r[k].x, a.x);
      a.y = fmaf(sc, r[k].y, a.y);
      a.z = fmaf(sc, r[k].z, a.z);
      a.w = fmaf(sc, r[k].w, a.w);
    }
  }
  nfloat4 av = {a.x, a.y, a.z, a.w};
  __builtin_nontemporal_store(av, (nfloat4*)agg + (sb + v) * 4 + ql);
}

// layer 3 GEMV: g3[r] = dinv[r] * sum_k relu(dinv[r]*agg2[r][k] + b2[k]) * W3[k]
// agg2 is slice-major [8][N][16]: lane l covers original k = 2l, 2l+1.
__global__ __launch_bounds__(256) void k_gemv3(const float* __restrict__ agg2, const float* __restrict__ W3,
                                               const float* __restrict__ dinv, const float* __restrict__ b2,
                                               float* __restrict__ g3, int N) {
  int wave = threadIdx.x >> 6;
  int lane = threadIdx.x & 63;
  int r = blockIdx.x * 4 + wave;
  if (r >= N) return;
  float di = dinv[r];
  float2 xv = ((const float2*)agg2)[((size_t)(lane >> 3) * N + r) * 8 + (lane & 7)];
  float2 wv = ((const float2*)W3)[lane];
  float2 bb = ((const float2*)b2)[lane];
  float v0 = fmaxf(fmaf(di, xv.x, bb.x), 0.f);
  float v1 = fmaxf(fmaf(di, xv.y, bb.y), 0.f);
  float s = v0 * wv.x + v1 * wv.y;
  for (int d = 32; d > 0; d >>= 1) s += __shfl_down(s, d, 64);
  if (lane == 0) g3[r] = di * s;
}

__global__ __launch_bounds__(256) void k_agg3(const float* __restrict__ g3, const int* __restrict__ offs,
                                              const int* __restrict__ csr_src, const float* __restrict__ dinv,
                                              const float* __restrict__ b3, float* __restrict__ out, int N) {
  int v = blockIdx.x * 256 + threadIdx.x;
  if (v < N) {
    float acc = g3[v];
    int i = offs[v], s1 = offs[v + 1];
    for (; i + 3 < s1; i += 4) {
      int e0 = csr_src[i], e1 = csr_src[i + 1], e2 = csr_src[i + 2], e3 = csr_src[i + 3];
      float r0 = g3[e0], r1 = g3[e1], r2 = g3[e2], r3 = g3[e3];
      acc += r0 + r1 + r2 + r3;
    }
    for (; i < s1; i++) acc += g3[csr_src[i]];
    out[v] = dinv[v] * acc + b3[0];
  }
}

extern "C" void kernel_launch(void* const* d_in, const int* in_sizes, int n_in,
                              void* d_out, int out_size, void* d_ws, size_t ws_size,
                              hipStream_t stream) {
  const float* x = (const float*)d_in[0];
  const int* ei = (const int*)d_in[1];
  const float* W1 = (const float*)d_in[2];
  const float* b1 = (const float*)d_in[3];
  const float* W2 = (const float*)d_in[4];
  const float* b2 = (const float*)d_in[5];
  const float* W3 = (const float*)d_in[6];
  const float* b3 = (const float*)d_in[7];
  float* out = (float*)d_out;

  int N = in_sizes[0] / 128;  // 50000
  int E = in_sizes[1] / 2;    // 800000

  char* base = (char*)d_ws;
  size_t off = 0;
  auto alloc = [&](size_t bytes) -> void* {
    void* p = base + off;
    off += (bytes + 255) & ~(size_t)255;
    return p;
  };
  int* cnt = (int*)alloc((size_t)N * 4);
  int* offs = (int*)alloc(((size_t)N + 1) * 4);
  int* cursor = (int*)alloc((size_t)N * 4);
  int* csr = (int*)alloc((size_t)E * 4);
  float* dinv = (float*)alloc((size_t)N * 4);
  int* bsum = (int*)alloc(4096 * 4);
  float* bufA = (float*)alloc((size_t)N * 128 * 4);
  float* bufB = (float*)alloc((size_t)N * 128 * 4);
  float* g3 = (float*)alloc((size_t)N * 4);
  (void)ws_size;

  (void)hipMemsetAsync(cnt, 0, (size_t)N * 4, stream);

  int gE = (E + 255) / 256;
  int gN = (N + 255) / 256;
  k_prep<<<gE, 256, 0, stream>>>(ei, cnt, E, N);
  k_scan1<<<gN, 256, 0, stream>>>(cnt, offs, bsum, dinv, N);
  k_scan2<<<1, 256, 0, stream>>>(bsum, gN);
  k_scan3<<<gN, 256, 0, stream>>>(offs, bsum, cursor, N, E);
  k_fill<<<gE, 256, 0, stream>>>(ei, cursor, csr, E, N);

  int gG = (N + 63) / 64;            // 782 blocks
  int gA = SLICES * gG;              // 6256 blocks: slice = b%8, chunk = b/8
  k_gemm<0><<<gG, 256, 0, stream>>>(x, W1, dinv, nullptr, bufA, N);
  k_agg<<<gA, 256, 0, stream>>>(bufA, offs, csr, bufB, N);
  k_gemm<1><<<gG, 256, 0, stream>>>(bufB, W2, dinv, b1, bufA, N);
  k_agg<<<gA, 256, 0, stream>>>(bufA, offs, csr, bufB, N);
  int gV = (N + 3) / 4;
  k_gemv3<<<gV, 256, 0, stream>>>(bufB, W3, dinv, b2, g3, N);
  k_agg3<<<gN, 256, 0, stream>>>(g3, offs, csr, dinv, b3, out, N);
}

// Round 11
// 357.902 us; speedup vs baseline: 1.0805x; 1.0805x over previous
//
#include <hip/hip_runtime.h>

// GCN 3-layer fused pipeline for MI355X.
// N=50000, E=800000, F=128. edge_index int32 [row[0..E), col[0..E)].
// R2:  wave-per-node float4 gathers: 85->58us (3.7 TB/s).
// R5:  deeper pipeline: 58->61us (occupancy offset). FETCH 185MB = 8-XCD refetch.
// R6-9: 8x64B feature slices + XCD %8 mapping: FETCH 185->37MB (L2-resident,
//      CONFIRMED) but dur flat 61us. Delivered BW ~7.2 TB/s in ALL variants ->
//      per-CU random-access ceiling (MSHR x latency), not HBM/L2 capacity.
// R10: granularity experiment: 4 slices x 128B (oct-lane gather) = same bytes,
//      HALF the requests. Distinguishes request-rate vs 64B-line-rate ceiling.
//      Also: scan1/2/3 merged into one kernel w/ device atomic barrier (12->10
//      dispatches; "rest" ~260us stable across rounds suggests ~10us/launch).
// R11: identical resubmit (R10 bench lost to GPU acquisition timeout).

#define SLICES 4

typedef float nfloat4 __attribute__((ext_vector_type(4)));

__global__ __launch_bounds__(256) void k_prep(const int* __restrict__ ei,
                                              int* __restrict__ cnt, int* __restrict__ ctr,
                                              int E, int N) {
  int e = blockIdx.x * 256 + threadIdx.x;
  if (e == 0) __hip_atomic_store(ctr, 0, __ATOMIC_RELAXED, __HIP_MEMORY_SCOPE_AGENT);
  if (e < E) {
    unsigned c = (unsigned)ei[E + e];
    if (c < (unsigned)N) atomicAdd(&cnt[c], 1);
  }
}

// Fused scan1+scan2+scan3: block-local scan -> post block sum -> device barrier
// (196 blocks, all co-resident; agent-scope atomics for cross-XCD coherence) ->
// each block sums predecessors' totals -> global offs/cursor/dinv in one pass.
__global__ __launch_bounds__(256) void k_scan(const int* __restrict__ cnt, int* __restrict__ offs,
                                              int* __restrict__ cursor, float* __restrict__ dinv,
                                              int* __restrict__ gsum, int* __restrict__ ctr,
                                              int N, int E, int NB) {
  __shared__ int s[256];
  int tid = threadIdx.x, b = blockIdx.x;
  int i = b * 256 + tid;
  int v = (i < N) ? cnt[i] : 0;
  if (i < N) dinv[i] = rsqrtf((float)(v + 1));  // +1 self loop; always > 0
  s[tid] = v;
  __syncthreads();
  for (int d = 1; d < 256; d <<= 1) {
    int t = (tid >= d) ? s[tid - d] : 0;
    __syncthreads();
    s[tid] += t;
    __syncthreads();
  }
  int lexcl = s[tid] - v;        // block-local exclusive prefix
  if (tid == 0) {
    __hip_atomic_store(&gsum[b], s[255], __ATOMIC_RELEASE, __HIP_MEMORY_SCOPE_AGENT);
    __hip_atomic_fetch_add(ctr, 1, __ATOMIC_ACQ_REL, __HIP_MEMORY_SCOPE_AGENT);
    while (__hip_atomic_load(ctr, __ATOMIC_ACQUIRE, __HIP_MEMORY_SCOPE_AGENT) < NB)
      __builtin_amdgcn_s_sleep(8);
  }
  __syncthreads();
  int part = (tid < b) ? __hip_atomic_load(&gsum[tid], __ATOMIC_RELAXED, __HIP_MEMORY_SCOPE_AGENT) : 0;
  s[tid] = part;
  __syncthreads();
  for (int d = 128; d > 0; d >>= 1) {
    if (tid < d) s[tid] += s[tid + d];
    __syncthreads();
  }
  int o = s[0] + lexcl;
  if (i < N) {
    offs[i] = o;
    cursor[i] = o;
  }
  if (i == 0) offs[N] = E;
}

__global__ __launch_bounds__(256) void k_fill(const int* __restrict__ ei,
                                              int* __restrict__ cursor, int* __restrict__ csr_src,
                                              int E, int N) {
  int e = blockIdx.x * 256 + threadIdx.x;
  if (e < E) {
    unsigned r = (unsigned)ei[e];
    unsigned c = (unsigned)ei[E + e];
    if (c < (unsigned)N && r < (unsigned)N) {
      int p = atomicAdd(&cursor[c], 1);
      csr_src[p] = (int)r;
    }
  }
}

// GEMM: G[s][row][32f] = dinv[row] * sum_k X'[row][k] * W[k][col], 4-slice-major out.
// Slice-major [4][N][32] keeps feature index = linear col -> bias indexing unchanged.
// MODE 0: X' = X row-major. MODE 1: X' = relu(dinv*X + b), X sliced.
template <int MODE>
__global__ __launch_bounds__(256) void k_gemm(const float* __restrict__ X, const float* __restrict__ W,
                                              const float* __restrict__ dinv, const float* __restrict__ bias,
                                              float* __restrict__ G, int N) {
  __shared__ float Wl[32 * 128];   // 16 KB (K-chunk of 32)
  __shared__ float Xl[64 * 128];   // 32 KB
  int tid = threadIdx.x;
  int row0 = blockIdx.x * 64;

  for (int i = tid; i < 2048; i += 256) {
    int r = i >> 5;
    int cc = i & 31;   // float4 column index; features cc*4..cc*4+3
    int grow = row0 + r;
    int gr = (grow < N) ? grow : (N - 1);
    float4 v;
    if (MODE == 0) {
      v = ((const float4*)X)[(size_t)gr * 32 + cc];
    } else {
      v = ((const float4*)X)[((size_t)(cc >> 3) * N + gr) * 8 + (cc & 7)];
      float di = dinv[gr];
      v.x = fmaxf(fmaf(di, v.x, bias[cc * 4 + 0]), 0.f);
      v.y = fmaxf(fmaf(di, v.y, bias[cc * 4 + 1]), 0.f);
      v.z = fmaxf(fmaf(di, v.z, bias[cc * 4 + 2]), 0.f);
      v.w = fmaxf(fmaf(di, v.w, bias[cc * 4 + 3]), 0.f);
    }
    ((float4*)Xl)[i] = v;
  }

  int cg = tid & 31;   // col group: cols cg*4..cg*4+3
  int rg = tid >> 5;   // row group: rows rg*8..rg*8+7
  float acc[8][4];
#pragma unroll
  for (int a = 0; a < 8; a++)
#pragma unroll
    for (int b = 0; b < 4; b++) acc[a][b] = 0.f;

  for (int kt = 0; kt < 4; kt++) {
    __syncthreads();
    for (int i = tid; i < 1024; i += 256)
      ((float4*)Wl)[i] = ((const float4*)W)[kt * 1024 + i];
    __syncthreads();
#pragma unroll
    for (int k4 = 0; k4 < 8; k4++) {
      float4 wv[4];
#pragma unroll
      for (int kk = 0; kk < 4; kk++)
        wv[kk] = ((const float4*)(Wl + (k4 * 4 + kk) * 128))[cg];
#pragma unroll
      for (int r = 0; r < 8; r++) {
        float4 xv = *(const float4*)(Xl + (rg * 8 + r) * 128 + kt * 32 + k4 * 4);
        acc[r][0] = fmaf(xv.x, wv[0].x, acc[r][0]);
        acc[r][1] = fmaf(xv.x, wv[0].y, acc[r][1]);
        acc[r][2] = fmaf(xv.x, wv[0].z, acc[r][2]);
        acc[r][3] = fmaf(xv.x, wv[0].w, acc[r][3]);
        acc[r][0] = fmaf(xv.y, wv[1].x, acc[r][0]);
        acc[r][1] = fmaf(xv.y, wv[1].y, acc[r][1]);
        acc[r][2] = fmaf(xv.y, wv[1].z, acc[r][2]);
        acc[r][3] = fmaf(xv.y, wv[1].w, acc[r][3]);
        acc[r][0] = fmaf(xv.z, wv[2].x, acc[r][0]);
        acc[r][1] = fmaf(xv.z, wv[2].y, acc[r][1]);
        acc[r][2] = fmaf(xv.z, wv[2].z, acc[r][2]);
        acc[r][3] = fmaf(xv.z, wv[2].w, acc[r][3]);
        acc[r][0] = fmaf(xv.w, wv[3].x, acc[r][0]);
        acc[r][1] = fmaf(xv.w, wv[3].y, acc[r][1]);
        acc[r][2] = fmaf(xv.w, wv[3].z, acc[r][2]);
        acc[r][3] = fmaf(xv.w, wv[3].w, acc[r][3]);
      }
    }
  }

  int s = cg >> 3, f8 = cg & 7;
#pragma unroll
  for (int ri = 0; ri < 8; ri++) {
    int grow = row0 + rg * 8 + ri;
    if (grow < N) {
      float di = dinv[grow];
      float4 o;
      o.x = di * acc[ri][0];
      o.y = di * acc[ri][1];
      o.z = di * acc[ri][2];
      o.w = di * acc[ri][3];
      ((float4*)G)[((size_t)s * N + grow) * 8 + f8] = o;
    }
  }
}

// Sliced aggregation, 128B granule: agg[s][v] = g[s][v] + sum g[s][src].
// slice = blockIdx&3. One node per 8-lane oct (8 lanes x float4 = 128B line).
// 8 edges in flight per oct; masked tail; no reduction shuffles.
__global__ __launch_bounds__(256) void k_agg(const float* __restrict__ g, const int* __restrict__ offs,
                                             const int* __restrict__ csr, float* __restrict__ agg, int N) {
  int s = blockIdx.x & 3;
  int chunk = blockIdx.x >> 2;
  int tid = threadIdx.x;
  int v = chunk * 32 + (tid >> 3);
  if (v >= N) return;
  int ol = tid & 7;            // float4 index within 128B slice line
  int o8 = (tid & 63) & ~7;    // oct base lane within wave
  const float4* __restrict__ G4 = (const float4*)g;
  size_t sb = (size_t)s * N;

  float4 a = G4[(sb + v) * 8 + ol];   // self slice line
  int s0 = offs[v], s1 = offs[v + 1];
  int last = s1 - 1;

  for (int i = s0; i < s1; i += 8) {
    int j = i + ol;
    int ia = __builtin_nontemporal_load(&csr[j < last ? j : last]);
    int srcs[8];
#pragma unroll
    for (int k = 0; k < 8; k++) srcs[k] = __shfl(ia, o8 + k, 64);
    float4 r[8];
#pragma unroll
    for (int k = 0; k < 8; k++) r[k] = G4[(sb + (size_t)srcs[k]) * 8 + ol];
#pragma unroll
    for (int k = 0; k < 8; k++) {
      float sc = (i + k < s1) ? 1.f : 0.f;
      a.x = fmaf(sc, r[k].x, a.x);
      a.y = fmaf(sc, r[k].y, a.y);
      a.z = fmaf(sc, r[k].z, a.z);
      a.w = fmaf(sc, r[k].w, a.w);
    }
  }
  nfloat4 av = {a.x, a.y, a.z, a.w};
  __builtin_nontemporal_store(av, (nfloat4*)agg + (sb + v) * 8 + ol);
}

// layer 3 GEMV: g3[r] = dinv[r] * sum_k relu(dinv[r]*agg2[r][k] + b2[k]) * W3[k]
// agg2 is slice-major [4][N][32]: lane l covers features 2l, 2l+1.
__global__ __launch_bounds__(256) void k_gemv3(const float* __restrict__ agg2, const float* __restrict__ W3,
                                               const float* __restrict__ dinv, const float* __restrict__ b2,
                                               float* __restrict__ g3, int N) {
  int wave = threadIdx.x >> 6;
  int lane = threadIdx.x & 63;
  int r = blockIdx.x * 4 + wave;
  if (r >= N) return;
  float di = dinv[r];
  float2 xv = ((const float2*)agg2)[((size_t)(lane >> 4) * N + r) * 16 + (lane & 15)];
  float2 wv = ((const float2*)W3)[lane];
  float2 bb = ((const float2*)b2)[lane];
  float v0 = fmaxf(fmaf(di, xv.x, bb.x), 0.f);
  float v1 = fmaxf(fmaf(di, xv.y, bb.y), 0.f);
  float s = v0 * wv.x + v1 * wv.y;
  for (int d = 32; d > 0; d >>= 1) s += __shfl_down(s, d, 64);
  if (lane == 0) g3[r] = di * s;
}

__global__ __launch_bounds__(256) void k_agg3(const float* __restrict__ g3, const int* __restrict__ offs,
                                              const int* __restrict__ csr_src, const float* __restrict__ dinv,
                                              const float* __restrict__ b3, float* __restrict__ out, int N) {
  int v = blockIdx.x * 256 + threadIdx.x;
  if (v < N) {
    float acc = g3[v];
    int i = offs[v], s1 = offs[v + 1];
    for (; i + 3 < s1; i += 4) {
      int e0 = csr_src[i], e1 = csr_src[i + 1], e2 = csr_src[i + 2], e3 = csr_src[i + 3];
      float r0 = g3[e0], r1 = g3[e1], r2 = g3[e2], r3 = g3[e3];
      acc += r0 + r1 + r2 + r3;
    }
    for (; i < s1; i++) acc += g3[csr_src[i]];
    out[v] = dinv[v] * acc + b3[0];
  }
}

extern "C" void kernel_launch(void* const* d_in, const int* in_sizes, int n_in,
                              void* d_out, int out_size, void* d_ws, size_t ws_size,
                              hipStream_t stream) {
  const float* x = (const float*)d_in[0];
  const int* ei = (const int*)d_in[1];
  const float* W1 = (const float*)d_in[2];
  const float* b1 = (const float*)d_in[3];
  const float* W2 = (const float*)d_in[4];
  const float* b2 = (const float*)d_in[5];
  const float* W3 = (const float*)d_in[6];
  const float* b3 = (const float*)d_in[7];
  float* out = (float*)d_out;

  int N = in_sizes[0] / 128;  // 50000
  int E = in_sizes[1] / 2;    // 800000

  char* base = (char*)d_ws;
  size_t off = 0;
  auto alloc = [&](size_t bytes) -> void* {
    void* p = base + off;
    off += (bytes + 255) & ~(size_t)255;
    return p;
  };
  int* cnt = (int*)alloc((size_t)N * 4);
  int* offs = (int*)alloc(((size_t)N + 1) * 4);
  int* cursor = (int*)alloc((size_t)N * 4);
  int* csr = (int*)alloc((size_t)E * 4);
  float* dinv = (float*)alloc((size_t)N * 4);
  int* gsum = (int*)alloc(4096 * 4);
  int* ctr = (int*)alloc(256);
  float* bufA = (float*)alloc((size_t)N * 128 * 4);
  float* bufB = (float*)alloc((size_t)N * 128 * 4);
  float* g3 = (float*)alloc((size_t)N * 4);
  (void)ws_size;

  (void)hipMemsetAsync(cnt, 0, (size_t)N * 4, stream);

  int gE = (E + 255) / 256;
  int gN = (N + 255) / 256;   // 196 blocks — all co-resident for k_scan's barrier
  k_prep<<<gE, 256, 0, stream>>>(ei, cnt, ctr, E, N);
  k_scan<<<gN, 256, 0, stream>>>(cnt, offs, cursor, dinv, gsum, ctr, N, E, gN);
  k_fill<<<gE, 256, 0, stream>>>(ei, cursor, csr, E, N);

  int gG = (N + 63) / 64;                  // 782 blocks
  int gA = SLICES * ((N + 31) / 32);       // 4 slices x 1563 chunks
  k_gemm<0><<<gG, 256, 0, stream>>>(x, W1, dinv, nullptr, bufA, N);
  k_agg<<<gA, 256, 0, stream>>>(bufA, offs, csr, bufB, N);
  k_gemm<1><<<gG, 256, 0, stream>>>(bufB, W2, dinv, b1, bufA, N);
  k_agg<<<gA, 256, 0, stream>>>(bufA, offs, csr, bufB, N);
  int gV = (N + 3) / 4;
  k_gemv3<<<gV, 256, 0, stream>>>(bufB, W3, dinv, b2, g3, N);
  k_agg3<<<gN, 256, 0, stream>>>(g3, offs, csr, dinv, b3, out, N);
}

// Round 12
// 346.374 us; speedup vs baseline: 1.1164x; 1.0333x over previous
//
#include <hip/hip_runtime.h>
#include <hip/hip_fp16.h>

// GCN 3-layer fused pipeline for MI355X.
// N=50000, E=800000, F=128. edge_index int32 [row[0..E), col[0..E)].
// R2-R11 findings: random-gather time tracks 64B LINES TOUCHED (~58us for 6.8M),
//   invariant to request size/count, L2 residency, MLP depth. GEMM was LDS-bound
//   (384 ds_read_b128/wave, 48KB LDS -> 3 blocks/CU, 15.6% occ).
// R12: (a) g stored fp16 row-major (256B/row = 4 lines/edge, HALF the lines);
//      (b) activation epilogue (relu(dinv*agg+b)) fused into k_agg -> GEMM is a
//          pure C=dinv*(X@W) for both layers;
//      (c) GEMM: X via global broadcast loads (no X-LDS, no staging sync), W-only
//          LDS 16KB -> ~5 blocks/CU, LDS instrs cut 3x; fp16 epilogue.

typedef float nfloat4 __attribute__((ext_vector_type(4)));

__global__ __launch_bounds__(256) void k_prep(const int* __restrict__ ei,
                                              int* __restrict__ cnt, int* __restrict__ ctr,
                                              int E, int N) {
  int e = blockIdx.x * 256 + threadIdx.x;
  if (e == 0) __hip_atomic_store(ctr, 0, __ATOMIC_RELAXED, __HIP_MEMORY_SCOPE_AGENT);
  if (e < E) {
    unsigned c = (unsigned)ei[E + e];
    if (c < (unsigned)N) atomicAdd(&cnt[c], 1);
  }
}

// Fused scan: block-local scan -> device barrier (196 co-resident blocks) ->
// cross-block offset -> offs/cursor/dinv in one pass.
__global__ __launch_bounds__(256) void k_scan(const int* __restrict__ cnt, int* __restrict__ offs,
                                              int* __restrict__ cursor, float* __restrict__ dinv,
                                              int* __restrict__ gsum, int* __restrict__ ctr,
                                              int N, int E, int NB) {
  __shared__ int s[256];
  int tid = threadIdx.x, b = blockIdx.x;
  int i = b * 256 + tid;
  int v = (i < N) ? cnt[i] : 0;
  if (i < N) dinv[i] = rsqrtf((float)(v + 1));  // +1 self loop; always > 0
  s[tid] = v;
  __syncthreads();
  for (int d = 1; d < 256; d <<= 1) {
    int t = (tid >= d) ? s[tid - d] : 0;
    __syncthreads();
    s[tid] += t;
    __syncthreads();
  }
  int lexcl = s[tid] - v;
  if (tid == 0) {
    __hip_atomic_store(&gsum[b], s[255], __ATOMIC_RELEASE, __HIP_MEMORY_SCOPE_AGENT);
    __hip_atomic_fetch_add(ctr, 1, __ATOMIC_ACQ_REL, __HIP_MEMORY_SCOPE_AGENT);
    while (__hip_atomic_load(ctr, __ATOMIC_ACQUIRE, __HIP_MEMORY_SCOPE_AGENT) < NB)
      __builtin_amdgcn_s_sleep(8);
  }
  __syncthreads();
  int part = (tid < b) ? __hip_atomic_load(&gsum[tid], __ATOMIC_RELAXED, __HIP_MEMORY_SCOPE_AGENT) : 0;
  s[tid] = part;
  __syncthreads();
  for (int d = 128; d > 0; d >>= 1) {
    if (tid < d) s[tid] += s[tid + d];
    __syncthreads();
  }
  int o = s[0] + lexcl;
  if (i < N) {
    offs[i] = o;
    cursor[i] = o;
  }
  if (i == 0) offs[N] = E;
}

__global__ __launch_bounds__(256) void k_fill(const int* __restrict__ ei,
                                              int* __restrict__ cursor, int* __restrict__ csr_src,
                                              int E, int N) {
  int e = blockIdx.x * 256 + threadIdx.x;
  if (e < E) {
    unsigned r = (unsigned)ei[e];
    unsigned c = (unsigned)ei[E + e];
    if (c < (unsigned)N && r < (unsigned)N) {
      int p = atomicAdd(&cursor[c], 1);
      csr_src[p] = (int)r;
    }
  }
}

// Pure GEMM: G[row][col] = fp16( dinv[row] * sum_k X[row][k]*W[k][col] ).
// 64 rows x 128 cols per block; thread = 8 rows x 4 cols.
// W staged in LDS (16KB per 32-k chunk). X read directly from global: all 32
// lanes of a row-group load the SAME address -> L1 broadcast (TA pipe, runs
// parallel to the LDS pipe). No X staging, no X sync.
__global__ __launch_bounds__(256) void k_gemm(const float* __restrict__ X, const float* __restrict__ W,
                                              const float* __restrict__ dinv, __half* __restrict__ G,
                                              int N) {
  __shared__ float Wl[32 * 128];   // 16 KB
  int tid = threadIdx.x;
  int row0 = blockIdx.x * 64;
  int cg = tid & 31;   // cols cg*4..cg*4+3
  int rg = tid >> 5;   // rows rg*8..rg*8+7
  const float4* __restrict__ X4 = (const float4*)X;

  size_t xb[8];
#pragma unroll
  for (int r = 0; r < 8; r++) {
    int grow = row0 + rg * 8 + r;
    xb[r] = (size_t)((grow < N) ? grow : (N - 1)) * 32;
  }

  float acc[8][4];
#pragma unroll
  for (int a = 0; a < 8; a++)
#pragma unroll
    for (int b = 0; b < 4; b++) acc[a][b] = 0.f;

  for (int kt = 0; kt < 4; kt++) {
    __syncthreads();
    for (int i = tid; i < 1024; i += 256)
      ((float4*)Wl)[i] = ((const float4*)W)[kt * 1024 + i];
    __syncthreads();
#pragma unroll
    for (int k4 = 0; k4 < 8; k4++) {
      float4 wv[4];
#pragma unroll
      for (int kk = 0; kk < 4; kk++)
        wv[kk] = ((const float4*)(Wl + (k4 * 4 + kk) * 128))[cg];
#pragma unroll
      for (int r = 0; r < 8; r++) {
        float4 xv = X4[xb[r] + kt * 8 + k4];   // broadcast across 32 lanes
        acc[r][0] = fmaf(xv.x, wv[0].x, acc[r][0]);
        acc[r][1] = fmaf(xv.x, wv[0].y, acc[r][1]);
        acc[r][2] = fmaf(xv.x, wv[0].z, acc[r][2]);
        acc[r][3] = fmaf(xv.x, wv[0].w, acc[r][3]);
        acc[r][0] = fmaf(xv.y, wv[1].x, acc[r][0]);
        acc[r][1] = fmaf(xv.y, wv[1].y, acc[r][1]);
        acc[r][2] = fmaf(xv.y, wv[1].z, acc[r][2]);
        acc[r][3] = fmaf(xv.y, wv[1].w, acc[r][3]);
        acc[r][0] = fmaf(xv.z, wv[2].x, acc[r][0]);
        acc[r][1] = fmaf(xv.z, wv[2].y, acc[r][1]);
        acc[r][2] = fmaf(xv.z, wv[2].z, acc[r][2]);
        acc[r][3] = fmaf(xv.z, wv[2].w, acc[r][3]);
        acc[r][0] = fmaf(xv.w, wv[3].x, acc[r][0]);
        acc[r][1] = fmaf(xv.w, wv[3].y, acc[r][1]);
        acc[r][2] = fmaf(xv.w, wv[3].z, acc[r][2]);
        acc[r][3] = fmaf(xv.w, wv[3].w, acc[r][3]);
      }
    }
  }

#pragma unroll
  for (int ri = 0; ri < 8; ri++) {
    int grow = row0 + rg * 8 + ri;
    if (grow < N) {
      float di = dinv[grow];
      __half2 h0 = __floats2half2_rn(di * acc[ri][0], di * acc[ri][1]);
      __half2 h1 = __floats2half2_rn(di * acc[ri][2], di * acc[ri][3]);
      uint2 u;
      u.x = *reinterpret_cast<unsigned*>(&h0);
      u.y = *reinterpret_cast<unsigned*>(&h1);
      ((uint2*)G)[(size_t)grow * 32 + cg] = u;
    }
  }
}

__device__ inline float4 cvt4(uint2 u) {
  __half2 a = *reinterpret_cast<__half2*>(&u.x);
  __half2 b = *reinterpret_cast<__half2*>(&u.y);
  float2 fa = __half22float2(a);
  float2 fb = __half22float2(b);
  return make_float4(fa.x, fa.y, fb.x, fb.y);
}

// Fused aggregate+activate: t[v] = relu(dinv[v]*(g[v] + sum g[src]) + bias).
// g is fp16 [N][128] (256B row = 4 cache lines, HALF of fp32). Wave per node;
// half-wave (32 lanes x 8B) = one row per load; halves own alternate edges;
// 4-deep pipeline -> 8 rows (32 lines) in flight per wave. fp32 accumulate.
__global__ __launch_bounds__(256) void k_agg(const __half* __restrict__ g, const int* __restrict__ offs,
                                             const int* __restrict__ csr, const float* __restrict__ dinv,
                                             const float* __restrict__ bias, float* __restrict__ t, int N) {
  int v = blockIdx.x * 4 + (threadIdx.x >> 6);
  if (v >= N) return;
  int lane = threadIdx.x & 63;
  int half = lane >> 5;
  int fc = lane & 31;   // features fc*4..fc*4+3
  const uint2* __restrict__ G2 = (const uint2*)g;

  float4 a0 = make_float4(0.f, 0.f, 0.f, 0.f);
  float4 a1 = make_float4(0.f, 0.f, 0.f, 0.f);
  if (half == 0) a0 = cvt4(G2[(size_t)v * 32 + fc]);   // self row

  int s0 = offs[v], s1 = offs[v + 1];
  int i = s0 + half;
  for (; i + 6 < s1; i += 8) {
    int e0 = csr[i];
    int e1 = csr[i + 2];
    int e2 = csr[i + 4];
    int e3 = csr[i + 6];
    uint2 r0 = G2[(size_t)e0 * 32 + fc];
    uint2 r1 = G2[(size_t)e1 * 32 + fc];
    uint2 r2 = G2[(size_t)e2 * 32 + fc];
    uint2 r3 = G2[(size_t)e3 * 32 + fc];
    float4 f0 = cvt4(r0), f1 = cvt4(r1), f2 = cvt4(r2), f3 = cvt4(r3);
    a0.x += f0.x; a0.y += f0.y; a0.z += f0.z; a0.w += f0.w;
    a1.x += f1.x; a1.y += f1.y; a1.z += f1.z; a1.w += f1.w;
    a0.x += f2.x; a0.y += f2.y; a0.z += f2.z; a0.w += f2.w;
    a1.x += f3.x; a1.y += f3.y; a1.z += f3.z; a1.w += f3.w;
  }
  for (; i < s1; i += 2) {
    float4 f = cvt4(G2[(size_t)csr[i] * 32 + fc]);
    a0.x += f.x; a0.y += f.y; a0.z += f.z; a0.w += f.w;
  }
  a0.x += a1.x; a0.y += a1.y; a0.z += a1.z; a0.w += a1.w;

  a0.x += __shfl_xor(a0.x, 32, 64);
  a0.y += __shfl_xor(a0.y, 32, 64);
  a0.z += __shfl_xor(a0.z, 32, 64);
  a0.w += __shfl_xor(a0.w, 32, 64);

  if (half == 0) {
    float di = dinv[v];
    float4 bb = ((const float4*)bias)[fc];
    float4 o;
    o.x = fmaxf(fmaf(di, a0.x, bb.x), 0.f);
    o.y = fmaxf(fmaf(di, a0.y, bb.y), 0.f);
    o.z = fmaxf(fmaf(di, a0.z, bb.z), 0.f);
    o.w = fmaxf(fmaf(di, a0.w, bb.w), 0.f);
    ((float4*)t)[(size_t)v * 32 + fc] = o;
  }
}

// layer 3 GEMV on pre-activated t2: g3[r] = dinv[r] * sum_k t2[r][k]*W3[k]
__global__ __launch_bounds__(256) void k_gemv3(const float* __restrict__ t2, const float* __restrict__ W3,
                                               const float* __restrict__ dinv, float* __restrict__ g3, int N) {
  int wave = threadIdx.x >> 6;
  int lane = threadIdx.x & 63;
  int r = blockIdx.x * 4 + wave;
  if (r >= N) return;
  float2 xv = ((const float2*)t2)[(size_t)r * 64 + lane];
  float2 wv = ((const float2*)W3)[lane];
  float s = xv.x * wv.x + xv.y * wv.y;
  for (int d = 32; d > 0; d >>= 1) s += __shfl_down(s, d, 64);
  if (lane == 0) g3[r] = dinv[r] * s;
}

__global__ __launch_bounds__(256) void k_agg3(const float* __restrict__ g3, const int* __restrict__ offs,
                                              const int* __restrict__ csr_src, const float* __restrict__ dinv,
                                              const float* __restrict__ b3, float* __restrict__ out, int N) {
  int v = blockIdx.x * 256 + threadIdx.x;
  if (v < N) {
    float acc = g3[v];
    int i = offs[v], s1 = offs[v + 1];
    for (; i + 3 < s1; i += 4) {
      int e0 = csr_src[i], e1 = csr_src[i + 1], e2 = csr_src[i + 2], e3 = csr_src[i + 3];
      float r0 = g3[e0], r1 = g3[e1], r2 = g3[e2], r3 = g3[e3];
      acc += r0 + r1 + r2 + r3;
    }
    for (; i < s1; i++) acc += g3[csr_src[i]];
    out[v] = dinv[v] * acc + b3[0];
  }
}

extern "C" void kernel_launch(void* const* d_in, const int* in_sizes, int n_in,
                              void* d_out, int out_size, void* d_ws, size_t ws_size,
                              hipStream_t stream) {
  const float* x = (const float*)d_in[0];
  const int* ei = (const int*)d_in[1];
  const float* W1 = (const float*)d_in[2];
  const float* b1 = (const float*)d_in[3];
  const float* W2 = (const float*)d_in[4];
  const float* b2 = (const float*)d_in[5];
  const float* W3 = (const float*)d_in[6];
  const float* b3 = (const float*)d_in[7];
  float* out = (float*)d_out;

  int N = in_sizes[0] / 128;  // 50000
  int E = in_sizes[1] / 2;    // 800000

  char* base = (char*)d_ws;
  size_t off = 0;
  auto alloc = [&](size_t bytes) -> void* {
    void* p = base + off;
    off += (bytes + 255) & ~(size_t)255;
    return p;
  };
  int* cnt = (int*)alloc((size_t)N * 4);
  int* offs = (int*)alloc(((size_t)N + 1) * 4);
  int* cursor = (int*)alloc((size_t)N * 4);
  int* csr = (int*)alloc((size_t)E * 4);
  float* dinv = (float*)alloc((size_t)N * 4);
  int* gsum = (int*)alloc(4096 * 4);
  int* ctr = (int*)alloc(256);
  __half* gH = (__half*)alloc((size_t)N * 128 * 2);   // fp16 gather buffer
  float* tA = (float*)alloc((size_t)N * 128 * 4);     // activated agg (f32)
  float* g3 = (float*)alloc((size_t)N * 4);
  (void)ws_size;

  (void)hipMemsetAsync(cnt, 0, (size_t)N * 4, stream);

  int gE = (E + 255) / 256;
  int gN = (N + 255) / 256;   // 196 blocks — co-resident for k_scan barrier
  k_prep<<<gE, 256, 0, stream>>>(ei, cnt, ctr, E, N);
  k_scan<<<gN, 256, 0, stream>>>(cnt, offs, cursor, dinv, gsum, ctr, N, E, gN);
  k_fill<<<gE, 256, 0, stream>>>(ei, cursor, csr, E, N);

  int gG = (N + 63) / 64;     // 782 blocks
  int gA = (N + 3) / 4;       // wave per node
  k_gemm<<<gG, 256, 0, stream>>>(x, W1, dinv, gH, N);
  k_agg<<<gA, 256, 0, stream>>>(gH, offs, csr, dinv, b1, tA, N);
  k_gemm<<<gG, 256, 0, stream>>>(tA, W2, dinv, gH, N);
  k_agg<<<gA, 256, 0, stream>>>(gH, offs, csr, dinv, b2, tA, N);
  k_gemv3<<<gA, 256, 0, stream>>>(tA, W3, dinv, g3, N);
  k_agg3<<<gN, 256, 0, stream>>>(g3, offs, csr, dinv, b3, out, N);
}

// Round 13
// 336.632 us; speedup vs baseline: 1.1488x; 1.0289x over previous
//
#include <hip/hip_runtime.h>
#include <hip/hip_fp16.h>

// GCN 3-layer fused pipeline for MI355X.
// N=50000, E=800000, F=128. edge_index int32 [row[0..E), col[0..E)].
// Established (R2-R12): random-gather time tracks 64B LINES TOUCHED
//   (~0.46 lines/cyc/CU), invariant to request size/count/L2-residency -> fp16
//   payload halved lines, k_agg ~30us = at ceiling. fp16 absmax 4.9e-4 (3.8x room).
// R13: (a) k_gemm 512-thread blocks (thread=4x4): 782 blocks x 8 waves = ~24
//          waves/CU (was 12) — occupancy was the binding constraint (22%, VALU 23%);
//      (b) k_fill XCD-sliced: block b (XCD b&7) handles dest-range slice only ->
//          cursor atomics + csr writes XCD-local/contiguous (was 52.5MB WRITE
//          from 16x partial-line amplification).

typedef float nfloat4 __attribute__((ext_vector_type(4)));

__global__ __launch_bounds__(256) void k_prep(const int* __restrict__ ei,
                                              int* __restrict__ cnt, int* __restrict__ ctr,
                                              int E, int N) {
  int e = blockIdx.x * 256 + threadIdx.x;
  if (e == 0) __hip_atomic_store(ctr, 0, __ATOMIC_RELAXED, __HIP_MEMORY_SCOPE_AGENT);
  if (e < E) {
    unsigned c = (unsigned)ei[E + e];
    if (c < (unsigned)N) atomicAdd(&cnt[c], 1);
  }
}

// Fused scan: block-local scan -> device barrier (196 co-resident blocks) ->
// cross-block offset -> offs/cursor/dinv in one pass.
__global__ __launch_bounds__(256) void k_scan(const int* __restrict__ cnt, int* __restrict__ offs,
                                              int* __restrict__ cursor, float* __restrict__ dinv,
                                              int* __restrict__ gsum, int* __restrict__ ctr,
                                              int N, int E, int NB) {
  __shared__ int s[256];
  int tid = threadIdx.x, b = blockIdx.x;
  int i = b * 256 + tid;
  int v = (i < N) ? cnt[i] : 0;
  if (i < N) dinv[i] = rsqrtf((float)(v + 1));  // +1 self loop; always > 0
  s[tid] = v;
  __syncthreads();
  for (int d = 1; d < 256; d <<= 1) {
    int t = (tid >= d) ? s[tid - d] : 0;
    __syncthreads();
    s[tid] += t;
    __syncthreads();
  }
  int lexcl = s[tid] - v;
  if (tid == 0) {
    __hip_atomic_store(&gsum[b], s[255], __ATOMIC_RELEASE, __HIP_MEMORY_SCOPE_AGENT);
    __hip_atomic_fetch_add(ctr, 1, __ATOMIC_ACQ_REL, __HIP_MEMORY_SCOPE_AGENT);
    while (__hip_atomic_load(ctr, __ATOMIC_ACQUIRE, __HIP_MEMORY_SCOPE_AGENT) < NB)
      __builtin_amdgcn_s_sleep(8);
  }
  __syncthreads();
  int part = (tid < b) ? __hip_atomic_load(&gsum[tid], __ATOMIC_RELAXED, __HIP_MEMORY_SCOPE_AGENT) : 0;
  s[tid] = part;
  __syncthreads();
  for (int d = 128; d > 0; d >>= 1) {
    if (tid < d) s[tid] += s[tid + d];
    __syncthreads();
  }
  int o = s[0] + lexcl;
  if (i < N) {
    offs[i] = o;
    cursor[i] = o;
  }
  if (i == 0) offs[N] = E;
}

// XCD-sliced fill: slice s = blockIdx&7 -> XCD s (round-robin dispatch, confirmed
// R9). Each slice scans its edge chunk but only takes edges with dest in its
// N/8 range -> cursor atomics and csr writes are XCD-local and contiguous.
__global__ __launch_bounds__(256) void k_fill(const int* __restrict__ ei,
                                              int* __restrict__ cursor, int* __restrict__ csr_src,
                                              int E, int N) {
  int s = blockIdx.x & 7;
  int chunk = blockIdx.x >> 3;
  int e = chunk * 256 + threadIdx.x;
  unsigned lo = (unsigned)((s * (long long)N) >> 3);
  unsigned hi = (unsigned)(((s + 1) * (long long)N) >> 3);
  if (e < E) {
    unsigned c = (unsigned)ei[E + e];
    if (c >= lo && c < hi) {
      unsigned r = (unsigned)ei[e];
      if (r < (unsigned)N) {
        int p = atomicAdd(&cursor[c], 1);
        csr_src[p] = (int)r;
      }
    }
  }
}

// Pure GEMM: G[row][col] = fp16( dinv[row] * sum_k X[row][k]*W[k][col] ).
// 512 threads: 64 rows x 128 cols per block; thread = 4 rows x 4 cols.
// 782 blocks x 8 waves -> ~24 waves/CU (occupancy was the R12 limiter).
// W staged in LDS (16KB per 32-k chunk); X via L1 broadcast loads (32 lanes
// of a row-group share the address).
__global__ __launch_bounds__(512) void k_gemm(const float* __restrict__ X, const float* __restrict__ W,
                                              const float* __restrict__ dinv, __half* __restrict__ G,
                                              int N) {
  __shared__ float Wl[32 * 128];   // 16 KB
  int tid = threadIdx.x;
  int row0 = blockIdx.x * 64;
  int cg = tid & 31;   // cols cg*4..cg*4+3
  int rg = tid >> 5;   // rows rg*4..rg*4+3 (rg 0..15)
  const float4* __restrict__ X4 = (const float4*)X;

  size_t xb[4];
#pragma unroll
  for (int r = 0; r < 4; r++) {
    int grow = row0 + rg * 4 + r;
    xb[r] = (size_t)((grow < N) ? grow : (N - 1)) * 32;
  }

  float acc[4][4];
#pragma unroll
  for (int a = 0; a < 4; a++)
#pragma unroll
    for (int b = 0; b < 4; b++) acc[a][b] = 0.f;

  for (int kt = 0; kt < 4; kt++) {
    __syncthreads();
    for (int i = tid; i < 1024; i += 512)
      ((float4*)Wl)[i] = ((const float4*)W)[kt * 1024 + i];
    __syncthreads();
#pragma unroll
    for (int k4 = 0; k4 < 8; k4++) {
      float4 wv[4];
#pragma unroll
      for (int kk = 0; kk < 4; kk++)
        wv[kk] = ((const float4*)(Wl + (k4 * 4 + kk) * 128))[cg];
#pragma unroll
      for (int r = 0; r < 4; r++) {
        float4 xv = X4[xb[r] + kt * 8 + k4];   // broadcast across 32 lanes
        acc[r][0] = fmaf(xv.x, wv[0].x, acc[r][0]);
        acc[r][1] = fmaf(xv.x, wv[0].y, acc[r][1]);
        acc[r][2] = fmaf(xv.x, wv[0].z, acc[r][2]);
        acc[r][3] = fmaf(xv.x, wv[0].w, acc[r][3]);
        acc[r][0] = fmaf(xv.y, wv[1].x, acc[r][0]);
        acc[r][1] = fmaf(xv.y, wv[1].y, acc[r][1]);
        acc[r][2] = fmaf(xv.y, wv[1].z, acc[r][2]);
        acc[r][3] = fmaf(xv.y, wv[1].w, acc[r][3]);
        acc[r][0] = fmaf(xv.z, wv[2].x, acc[r][0]);
        acc[r][1] = fmaf(xv.z, wv[2].y, acc[r][1]);
        acc[r][2] = fmaf(xv.z, wv[2].z, acc[r][2]);
        acc[r][3] = fmaf(xv.z, wv[2].w, acc[r][3]);
        acc[r][0] = fmaf(xv.w, wv[3].x, acc[r][0]);
        acc[r][1] = fmaf(xv.w, wv[3].y, acc[r][1]);
        acc[r][2] = fmaf(xv.w, wv[3].z, acc[r][2]);
        acc[r][3] = fmaf(xv.w, wv[3].w, acc[r][3]);
      }
    }
  }

#pragma unroll
  for (int ri = 0; ri < 4; ri++) {
    int grow = row0 + rg * 4 + ri;
    if (grow < N) {
      float di = dinv[grow];
      __half2 h0 = __floats2half2_rn(di * acc[ri][0], di * acc[ri][1]);
      __half2 h1 = __floats2half2_rn(di * acc[ri][2], di * acc[ri][3]);
      uint2 u;
      u.x = *reinterpret_cast<unsigned*>(&h0);
      u.y = *reinterpret_cast<unsigned*>(&h1);
      ((uint2*)G)[(size_t)grow * 32 + cg] = u;
    }
  }
}

__device__ inline float4 cvt4(uint2 u) {
  __half2 a = *reinterpret_cast<__half2*>(&u.x);
  __half2 b = *reinterpret_cast<__half2*>(&u.y);
  float2 fa = __half22float2(a);
  float2 fb = __half22float2(b);
  return make_float4(fa.x, fa.y, fb.x, fb.y);
}

// Fused aggregate+activate: t[v] = relu(dinv[v]*(g[v] + sum g[src]) + bias).
// g is fp16 [N][128] (256B row = 4 cache lines). Wave per node; half-wave
// (32 lanes x 8B) = one row; halves own alternate edges; 4-deep pipeline.
__global__ __launch_bounds__(256) void k_agg(const __half* __restrict__ g, const int* __restrict__ offs,
                                             const int* __restrict__ csr, const float* __restrict__ dinv,
                                             const float* __restrict__ bias, float* __restrict__ t, int N) {
  int v = blockIdx.x * 4 + (threadIdx.x >> 6);
  if (v >= N) return;
  int lane = threadIdx.x & 63;
  int half = lane >> 5;
  int fc = lane & 31;   // features fc*4..fc*4+3
  const uint2* __restrict__ G2 = (const uint2*)g;

  float4 a0 = make_float4(0.f, 0.f, 0.f, 0.f);
  float4 a1 = make_float4(0.f, 0.f, 0.f, 0.f);
  if (half == 0) a0 = cvt4(G2[(size_t)v * 32 + fc]);   // self row

  int s0 = offs[v], s1 = offs[v + 1];
  int i = s0 + half;
  for (; i + 6 < s1; i += 8) {
    int e0 = csr[i];
    int e1 = csr[i + 2];
    int e2 = csr[i + 4];
    int e3 = csr[i + 6];
    uint2 r0 = G2[(size_t)e0 * 32 + fc];
    uint2 r1 = G2[(size_t)e1 * 32 + fc];
    uint2 r2 = G2[(size_t)e2 * 32 + fc];
    uint2 r3 = G2[(size_t)e3 * 32 + fc];
    float4 f0 = cvt4(r0), f1 = cvt4(r1), f2 = cvt4(r2), f3 = cvt4(r3);
    a0.x += f0.x; a0.y += f0.y; a0.z += f0.z; a0.w += f0.w;
    a1.x += f1.x; a1.y += f1.y; a1.z += f1.z; a1.w += f1.w;
    a0.x += f2.x; a0.y += f2.y; a0.z += f2.z; a0.w += f2.w;
    a1.x += f3.x; a1.y += f3.y; a1.z += f3.z; a1.w += f3.w;
  }
  for (; i < s1; i += 2) {
    float4 f = cvt4(G2[(size_t)csr[i] * 32 + fc]);
    a0.x += f.x; a0.y += f.y; a0.z += f.z; a0.w += f.w;
  }
  a0.x += a1.x; a0.y += a1.y; a0.z += a1.z; a0.w += a1.w;

  a0.x += __shfl_xor(a0.x, 32, 64);
  a0.y += __shfl_xor(a0.y, 32, 64);
  a0.z += __shfl_xor(a0.z, 32, 64);
  a0.w += __shfl_xor(a0.w, 32, 64);

  if (half == 0) {
    float di = dinv[v];
    float4 bb = ((const float4*)bias)[fc];
    float4 o;
    o.x = fmaxf(fmaf(di, a0.x, bb.x), 0.f);
    o.y = fmaxf(fmaf(di, a0.y, bb.y), 0.f);
    o.z = fmaxf(fmaf(di, a0.z, bb.z), 0.f);
    o.w = fmaxf(fmaf(di, a0.w, bb.w), 0.f);
    ((float4*)t)[(size_t)v * 32 + fc] = o;
  }
}

// layer 3 GEMV on pre-activated t2: g3[r] = dinv[r] * sum_k t2[r][k]*W3[k]
__global__ __launch_bounds__(256) void k_gemv3(const float* __restrict__ t2, const float* __restrict__ W3,
                                               const float* __restrict__ dinv, float* __restrict__ g3, int N) {
  int wave = threadIdx.x >> 6;
  int lane = threadIdx.x & 63;
  int r = blockIdx.x * 4 + wave;
  if (r >= N) return;
  float2 xv = ((const float2*)t2)[(size_t)r * 64 + lane];
  float2 wv = ((const float2*)W3)[lane];
  float s = xv.x * wv.x + xv.y * wv.y;
  for (int d = 32; d > 0; d >>= 1) s += __shfl_down(s, d, 64);
  if (lane == 0) g3[r] = dinv[r] * s;
}

__global__ __launch_bounds__(256) void k_agg3(const float* __restrict__ g3, const int* __restrict__ offs,
                                              const int* __restrict__ csr_src, const float* __restrict__ dinv,
                                              const float* __restrict__ b3, float* __restrict__ out, int N) {
  int v = blockIdx.x * 256 + threadIdx.x;
  if (v < N) {
    float acc = g3[v];
    int i = offs[v], s1 = offs[v + 1];
    for (; i + 3 < s1; i += 4) {
      int e0 = csr_src[i], e1 = csr_src[i + 1], e2 = csr_src[i + 2], e3 = csr_src[i + 3];
      float r0 = g3[e0], r1 = g3[e1], r2 = g3[e2], r3 = g3[e3];
      acc += r0 + r1 + r2 + r3;
    }
    for (; i < s1; i++) acc += g3[csr_src[i]];
    out[v] = dinv[v] * acc + b3[0];
  }
}

extern "C" void kernel_launch(void* const* d_in, const int* in_sizes, int n_in,
                              void* d_out, int out_size, void* d_ws, size_t ws_size,
                              hipStream_t stream) {
  const float* x = (const float*)d_in[0];
  const int* ei = (const int*)d_in[1];
  const float* W1 = (const float*)d_in[2];
  const float* b1 = (const float*)d_in[3];
  const float* W2 = (const float*)d_in[4];
  const float* b2 = (const float*)d_in[5];
  const float* W3 = (const float*)d_in[6];
  const float* b3 = (const float*)d_in[7];
  float* out = (float*)d_out;

  int N = in_sizes[0] / 128;  // 50000
  int E = in_sizes[1] / 2;    // 800000

  char* base = (char*)d_ws;
  size_t off = 0;
  auto alloc = [&](size_t bytes) -> void* {
    void* p = base + off;
    off += (bytes + 255) & ~(size_t)255;
    return p;
  };
  int* cnt = (int*)alloc((size_t)N * 4);
  int* offs = (int*)alloc(((size_t)N + 1) * 4);
  int* cursor = (int*)alloc((size_t)N * 4);
  int* csr = (int*)alloc((size_t)E * 4);
  float* dinv = (float*)alloc((size_t)N * 4);
  int* gsum = (int*)alloc(4096 * 4);
  int* ctr = (int*)alloc(256);
  __half* gH = (__half*)alloc((size_t)N * 128 * 2);   // fp16 gather buffer
  float* tA = (float*)alloc((size_t)N * 128 * 4);     // activated agg (f32)
  float* g3 = (float*)alloc((size_t)N * 4);
  (void)ws_size;

  (void)hipMemsetAsync(cnt, 0, (size_t)N * 4, stream);

  int gE = (E + 255) / 256;
  int gN = (N + 255) / 256;   // 196 blocks — co-resident for k_scan barrier
  k_prep<<<gE, 256, 0, stream>>>(ei, cnt, ctr, E, N);
  k_scan<<<gN, 256, 0, stream>>>(cnt, offs, cursor, dinv, gsum, ctr, N, E, gN);
  k_fill<<<8 * gE, 256, 0, stream>>>(ei, cursor, csr, E, N);

  int gG = (N + 63) / 64;     // 782 blocks x 512 threads
  int gA = (N + 3) / 4;       // wave per node
  k_gemm<<<gG, 512, 0, stream>>>(x, W1, dinv, gH, N);
  k_agg<<<gA, 256, 0, stream>>>(gH, offs, csr, dinv, b1, tA, N);
  k_gemm<<<gG, 512, 0, stream>>>(tA, W2, dinv, gH, N);
  k_agg<<<gA, 256, 0, stream>>>(gH, offs, csr, dinv, b2, tA, N);
  k_gemv3<<<gA, 256, 0, stream>>>(tA, W3, dinv, g3, N);
  k_agg3<<<gN, 256, 0, stream>>>(g3, offs, csr, dinv, b3, out, N);
}

// Round 14
// 280.531 us; speedup vs baseline: 1.3785x; 1.2000x over previous
//
#include <hip/hip_runtime.h>
#include <hip/hip_fp16.h>

// GCN 3-layer fused pipeline for MI355X.
// N=50000, E=800000, F=128. edge_index int32 [row[0..E), col[0..E)].
// Established: random-gather = 64B-lines-touched ceiling -> fp16 g rows (R12);
//   f32 FMA GEMM is load-latency-chain bound (two occupancy levers failed, R12/R13).
// R14: GEMMs -> MFMA f32_16x16x32_f16. W pre-converted to transposed+swizzled
//   fp16 Wt[col][k] (fused into k_scan); 4-wave block = 64 rows x 128 cols;
//   one 32KB LDS stage + single barrier; A-frags cvt from f32 X in-register
//   (tA stays f32 -> minimal numerics diff). B ds_read conflict killed by
//   byte ^= (col&7)<<4 swizzle (pre-applied at Wt generation).

typedef float nfloat4 __attribute__((ext_vector_type(4)));
typedef _Float16 half8 __attribute__((ext_vector_type(8)));
typedef float f32x4 __attribute__((ext_vector_type(4)));

__global__ __launch_bounds__(256) void k_prep(const int* __restrict__ ei,
                                              int* __restrict__ cnt, int* __restrict__ ctr,
                                              int E, int N) {
  int e = blockIdx.x * 256 + threadIdx.x;
  if (e == 0) __hip_atomic_store(ctr, 0, __ATOMIC_RELAXED, __HIP_MEMORY_SCOPE_AGENT);
  if (e < E) {
    unsigned c = (unsigned)ei[E + e];
    if (c < (unsigned)N) atomicAdd(&cnt[c], 1);
  }
}

// Fused scan + W-convert: converts W1/W2 (f32 [k][col]) to fp16 transposed
// swizzled Wt[col][k] at byte col*256 + ((k*2)^((col&7)<<4)); then block-local
// scan -> device barrier (196 co-resident blocks) -> offs/cursor/dinv.
__global__ __launch_bounds__(256) void k_scan(const int* __restrict__ cnt, int* __restrict__ offs,
                                              int* __restrict__ cursor, float* __restrict__ dinv,
                                              int* __restrict__ gsum, int* __restrict__ ctr,
                                              const float* __restrict__ W1, const float* __restrict__ W2,
                                              _Float16* __restrict__ WtA, _Float16* __restrict__ WtB,
                                              int N, int E, int NB) {
  __shared__ int s[256];
  int tid = threadIdx.x, b = blockIdx.x;
  int i = b * 256 + tid;

  // W convert (independent work, before barrier)
  if (i < 32768) {
    int which = i >> 14, e = i & 16383;
    int c = e >> 7, k = e & 127;
    const float* Wsrc = which ? W2 : W1;
    _Float16 h = (_Float16)Wsrc[k * 128 + c];
    char* dst = (char*)(which ? WtB : WtA);
    *(_Float16*)(dst + c * 256 + ((k * 2) ^ ((c & 7) << 4))) = h;
  }

  int v = (i < N) ? cnt[i] : 0;
  if (i < N) dinv[i] = rsqrtf((float)(v + 1));  // +1 self loop; always > 0
  s[tid] = v;
  __syncthreads();
  for (int d = 1; d < 256; d <<= 1) {
    int t = (tid >= d) ? s[tid - d] : 0;
    __syncthreads();
    s[tid] += t;
    __syncthreads();
  }
  int lexcl = s[tid] - v;
  if (tid == 0) {
    __hip_atomic_store(&gsum[b], s[255], __ATOMIC_RELEASE, __HIP_MEMORY_SCOPE_AGENT);
    __hip_atomic_fetch_add(ctr, 1, __ATOMIC_ACQ_REL, __HIP_MEMORY_SCOPE_AGENT);
    while (__hip_atomic_load(ctr, __ATOMIC_ACQUIRE, __HIP_MEMORY_SCOPE_AGENT) < NB)
      __builtin_amdgcn_s_sleep(8);
  }
  __syncthreads();
  int part = (tid < b) ? __hip_atomic_load(&gsum[tid], __ATOMIC_RELAXED, __HIP_MEMORY_SCOPE_AGENT) : 0;
  s[tid] = part;
  __syncthreads();
  for (int d = 128; d > 0; d >>= 1) {
    if (tid < d) s[tid] += s[tid + d];
    __syncthreads();
  }
  int o = s[0] + lexcl;
  if (i < N) {
    offs[i] = o;
    cursor[i] = o;
  }
  if (i == 0) offs[N] = E;
}

// XCD-sliced fill (R13): slice s = blockIdx&7 handles dest range [s*N/8,(s+1)*N/8).
__global__ __launch_bounds__(256) void k_fill(const int* __restrict__ ei,
                                              int* __restrict__ cursor, int* __restrict__ csr_src,
                                              int E, int N) {
  int s = blockIdx.x & 7;
  int chunk = blockIdx.x >> 3;
  int e = chunk * 256 + threadIdx.x;
  unsigned lo = (unsigned)((s * (long long)N) >> 3);
  unsigned hi = (unsigned)(((s + 1) * (long long)N) >> 3);
  if (e < E) {
    unsigned c = (unsigned)ei[E + e];
    if (c >= lo && c < hi) {
      unsigned r = (unsigned)ei[e];
      if (r < (unsigned)N) {
        int p = atomicAdd(&cursor[c], 1);
        csr_src[p] = (int)r;
      }
    }
  }
}

// MFMA GEMM: G[row][col] = fp16( dinv[row] * sum_k X[row][k]*W[k][col] ).
// X f32 [N][128] (converted to fp16 fragments in-register);
// Wt fp16 transposed+swizzled [col][k]. Block = 4 waves, 64 rows x 128 cols.
// Per wave: 4 A-frags (K=32 each), 8 col-groups x 4 MFMA.
// A layout: row=l&15, k=(l>>4)*8+j.  B: k=(l>>4)*8+j, col=l&15.
// C/D: col=l&15, row=(l>>4)*4+reg (guide-verified).
__global__ __launch_bounds__(256) void k_gemm(const float* __restrict__ X,
                                              const _Float16* __restrict__ Wt,
                                              const float* __restrict__ dinv,
                                              __half* __restrict__ G, int N) {
  __shared__ _Float16 Wl[128 * 128];   // 32 KB, swizzled layout (linear copy)
  int tid = threadIdx.x;
  int w = tid >> 6;          // wave 0..3
  int l = tid & 63;          // lane
  int cl = l & 15;
  int kg = l >> 4;           // 0..3
  int row0 = blockIdx.x * 64 + w * 16;

  for (int i = tid; i < 2048; i += 256)
    ((uint4*)Wl)[i] = ((const uint4*)Wt)[i];
  __syncthreads();

  // A fragments: rows row0+cl, k = k0*32 + kg*8 + j  (f32 -> fp16 cvt)
  int ra = row0 + cl;
  size_t xb = (size_t)((ra < N) ? ra : (N - 1)) * 32;
  const float4* __restrict__ X4 = (const float4*)X;
  half8 a[4];
#pragma unroll
  for (int k0 = 0; k0 < 4; k0++) {
    float4 f0 = X4[xb + k0 * 8 + kg * 2];
    float4 f1 = X4[xb + k0 * 8 + kg * 2 + 1];
    half8 h;
    h[0] = (_Float16)f0.x; h[1] = (_Float16)f0.y;
    h[2] = (_Float16)f0.z; h[3] = (_Float16)f0.w;
    h[4] = (_Float16)f1.x; h[5] = (_Float16)f1.y;
    h[6] = (_Float16)f1.z; h[7] = (_Float16)f1.w;
    a[k0] = h;
  }

  // dinv for this lane's C/D rows
  int rowc = row0 + kg * 4;
  float dv[4];
#pragma unroll
  for (int r = 0; r < 4; r++) {
    int rc = rowc + r;
    dv[r] = dinv[(rc < N) ? rc : (N - 1)];
  }

#pragma unroll
  for (int g = 0; g < 8; g++) {
    int col = g * 16 + cl;
    int swz = (col & 7) << 4;
    f32x4 acc = {0.f, 0.f, 0.f, 0.f};
#pragma unroll
    for (int k0 = 0; k0 < 4; k0++) {
      int byteoff = col * 256 + ((k0 * 64 + kg * 16) ^ swz);
      half8 bfrag = *(const half8*)((const char*)Wl + byteoff);
      acc = __builtin_amdgcn_mfma_f32_16x16x32_f16(a[k0], bfrag, acc, 0, 0, 0);
    }
#pragma unroll
    for (int r = 0; r < 4; r++) {
      int rc = rowc + r;
      if (rc < N) G[(size_t)rc * 128 + g * 16 + cl] = __float2half_rn(dv[r] * acc[r]);
    }
  }
}

__device__ inline float4 cvt4(uint2 u) {
  __half2 a = *reinterpret_cast<__half2*>(&u.x);
  __half2 b = *reinterpret_cast<__half2*>(&u.y);
  float2 fa = __half22float2(a);
  float2 fb = __half22float2(b);
  return make_float4(fa.x, fa.y, fb.x, fb.y);
}

// Fused aggregate+activate: t[v] = relu(dinv[v]*(g[v] + sum g[src]) + bias).
// g fp16 [N][128]. Wave per node; half-wave = one row; 4-deep pipeline.
__global__ __launch_bounds__(256) void k_agg(const __half* __restrict__ g, const int* __restrict__ offs,
                                             const int* __restrict__ csr, const float* __restrict__ dinv,
                                             const float* __restrict__ bias, float* __restrict__ t, int N) {
  int v = blockIdx.x * 4 + (threadIdx.x >> 6);
  if (v >= N) return;
  int lane = threadIdx.x & 63;
  int half = lane >> 5;
  int fc = lane & 31;   // features fc*4..fc*4+3
  const uint2* __restrict__ G2 = (const uint2*)g;

  float4 a0 = make_float4(0.f, 0.f, 0.f, 0.f);
  float4 a1 = make_float4(0.f, 0.f, 0.f, 0.f);
  if (half == 0) a0 = cvt4(G2[(size_t)v * 32 + fc]);   // self row

  int s0 = offs[v], s1 = offs[v + 1];
  int i = s0 + half;
  for (; i + 6 < s1; i += 8) {
    int e0 = csr[i];
    int e1 = csr[i + 2];
    int e2 = csr[i + 4];
    int e3 = csr[i + 6];
    uint2 r0 = G2[(size_t)e0 * 32 + fc];
    uint2 r1 = G2[(size_t)e1 * 32 + fc];
    uint2 r2 = G2[(size_t)e2 * 32 + fc];
    uint2 r3 = G2[(size_t)e3 * 32 + fc];
    float4 f0 = cvt4(r0), f1 = cvt4(r1), f2 = cvt4(r2), f3 = cvt4(r3);
    a0.x += f0.x; a0.y += f0.y; a0.z += f0.z; a0.w += f0.w;
    a1.x += f1.x; a1.y += f1.y; a1.z += f1.z; a1.w += f1.w;
    a0.x += f2.x; a0.y += f2.y; a0.z += f2.z; a0.w += f2.w;
    a1.x += f3.x; a1.y += f3.y; a1.z += f3.z; a1.w += f3.w;
  }
  for (; i < s1; i += 2) {
    float4 f = cvt4(G2[(size_t)csr[i] * 32 + fc]);
    a0.x += f.x; a0.y += f.y; a0.z += f.z; a0.w += f.w;
  }
  a0.x += a1.x; a0.y += a1.y; a0.z += a1.z; a0.w += a1.w;

  a0.x += __shfl_xor(a0.x, 32, 64);
  a0.y += __shfl_xor(a0.y, 32, 64);
  a0.z += __shfl_xor(a0.z, 32, 64);
  a0.w += __shfl_xor(a0.w, 32, 64);

  if (half == 0) {
    float di = dinv[v];
    float4 bb = ((const float4*)bias)[fc];
    float4 o;
    o.x = fmaxf(fmaf(di, a0.x, bb.x), 0.f);
    o.y = fmaxf(fmaf(di, a0.y, bb.y), 0.f);
    o.z = fmaxf(fmaf(di, a0.z, bb.z), 0.f);
    o.w = fmaxf(fmaf(di, a0.w, bb.w), 0.f);
    ((float4*)t)[(size_t)v * 32 + fc] = o;
  }
}

// layer 3 GEMV on pre-activated t2 (f32): g3[r] = dinv[r] * sum_k t2[r][k]*W3[k]
__global__ __launch_bounds__(256) void k_gemv3(const float* __restrict__ t2, const float* __restrict__ W3,
                                               const float* __restrict__ dinv, float* __restrict__ g3, int N) {
  int wave = threadIdx.x >> 6;
  int lane = threadIdx.x & 63;
  int r = blockIdx.x * 4 + wave;
  if (r >= N) return;
  float2 xv = ((const float2*)t2)[(size_t)r * 64 + lane];
  float2 wv = ((const float2*)W3)[lane];
  float s = xv.x * wv.x + xv.y * wv.y;
  for (int d = 32; d > 0; d >>= 1) s += __shfl_down(s, d, 64);
  if (lane == 0) g3[r] = dinv[r] * s;
}

__global__ __launch_bounds__(256) void k_agg3(const float* __restrict__ g3, const int* __restrict__ offs,
                                              const int* __restrict__ csr_src, const float* __restrict__ dinv,
                                              const float* __restrict__ b3, float* __restrict__ out, int N) {
  int v = blockIdx.x * 256 + threadIdx.x;
  if (v < N) {
    float acc = g3[v];
    int i = offs[v], s1 = offs[v + 1];
    for (; i + 3 < s1; i += 4) {
      int e0 = csr_src[i], e1 = csr_src[i + 1], e2 = csr_src[i + 2], e3 = csr_src[i + 3];
      float r0 = g3[e0], r1 = g3[e1], r2 = g3[e2], r3 = g3[e3];
      acc += r0 + r1 + r2 + r3;
    }
    for (; i < s1; i++) acc += g3[csr_src[i]];
    out[v] = dinv[v] * acc + b3[0];
  }
}

extern "C" void kernel_launch(void* const* d_in, const int* in_sizes, int n_in,
                              void* d_out, int out_size, void* d_ws, size_t ws_size,
                              hipStream_t stream) {
  const float* x = (const float*)d_in[0];
  const int* ei = (const int*)d_in[1];
  const float* W1 = (const float*)d_in[2];
  const float* b1 = (const float*)d_in[3];
  const float* W2 = (const float*)d_in[4];
  const float* b2 = (const float*)d_in[5];
  const float* W3 = (const float*)d_in[6];
  const float* b3 = (const float*)d_in[7];
  float* out = (float*)d_out;

  int N = in_sizes[0] / 128;  // 50000
  int E = in_sizes[1] / 2;    // 800000

  char* base = (char*)d_ws;
  size_t off = 0;
  auto alloc = [&](size_t bytes) -> void* {
    void* p = base + off;
    off += (bytes + 255) & ~(size_t)255;
    return p;
  };
  int* cnt = (int*)alloc((size_t)N * 4);
  int* offs = (int*)alloc(((size_t)N + 1) * 4);
  int* cursor = (int*)alloc((size_t)N * 4);
  int* csr = (int*)alloc((size_t)E * 4);
  float* dinv = (float*)alloc((size_t)N * 4);
  int* gsum = (int*)alloc(4096 * 4);
  int* ctr = (int*)alloc(256);
  _Float16* WtA = (_Float16*)alloc(128 * 128 * 2);    // swizzled fp16 W1^T
  _Float16* WtB = (_Float16*)alloc(128 * 128 * 2);    // swizzled fp16 W2^T
  __half* gH = (__half*)alloc((size_t)N * 128 * 2);   // fp16 gather buffer
  float* tA = (float*)alloc((size_t)N * 128 * 4);     // activated agg (f32)
  float* g3 = (float*)alloc((size_t)N * 4);
  (void)ws_size;

  (void)hipMemsetAsync(cnt, 0, (size_t)N * 4, stream);

  int gE = (E + 255) / 256;
  int gN = (N + 255) / 256;   // 196 blocks — co-resident for k_scan barrier
  k_prep<<<gE, 256, 0, stream>>>(ei, cnt, ctr, E, N);
  k_scan<<<gN, 256, 0, stream>>>(cnt, offs, cursor, dinv, gsum, ctr, W1, W2, WtA, WtB, N, E, gN);
  k_fill<<<8 * gE, 256, 0, stream>>>(ei, cursor, csr, E, N);

  int gG = (N + 63) / 64;     // 782 blocks x 256 threads (4 waves)
  int gA = (N + 3) / 4;       // wave per node
  k_gemm<<<gG, 256, 0, stream>>>(x, WtA, dinv, gH, N);
  k_agg<<<gA, 256, 0, stream>>>(gH, offs, csr, dinv, b1, tA, N);
  k_gemm<<<gG, 256, 0, stream>>>(tA, WtB, dinv, gH, N);
  k_agg<<<gA, 256, 0, stream>>>(gH, offs, csr, dinv, b2, tA, N);
  k_gemv3<<<gA, 256, 0, stream>>>(tA, W3, dinv, g3, N);
  k_agg3<<<gN, 256, 0, stream>>>(g3, offs, csr, dinv, b3, out, N);
}